// Round 38
// baseline (93.470 us; speedup 1.0000x reference)
//
#include <hip/hip_runtime.h>
#include <math.h>

#define BN_ 32768
#define SPP_ 64
#define HID_ 64

__device__ __forceinline__ float softplus_f(float x) {
    return fmaxf(x, 0.f) + log1pf(__expf(-fabsf(x)));
}

__global__ __launch_bounds__(256) void render_kernel(
    const float* __restrict__ sp,    // (BN,3) surface_points
    const float* __restrict__ vd,    // (BN,3) view_direction
    const float* __restrict__ Kd,    // (BN,3)
    const float* __restrict__ Ks,    // (BN,3)
    const float* __restrict__ nrm,   // (BN,3) normal
    const float* __restrict__ rough, // (BN,1)
    const float* __restrict__ smp,   // (BN,SPP,3)
    const float* __restrict__ W1,    // (6,64)
    const float* __restrict__ b1,    // (64,)
    const float* __restrict__ W2,    // (64,3)
    const float* __restrict__ b2,    // (3,)
    float* __restrict__ out)         // [BN*3 diffuse][BN*3 spec][BN wi_mask]
{
    const float PI_F = 3.14159265358979323846f;

    // Packed weight rows: {W1[0][j]..W1[5][j], b1[j], 0, W2[j][0..2], 0}
    __shared__ __align__(16) float sPack[64][12];
    __shared__ float sb2[4];

    const int tid = threadIdx.x;
    if (tid < 64) {
        const int j = tid;
        sPack[j][0]  = W1[0 * 64 + j];
        sPack[j][1]  = W1[1 * 64 + j];
        sPack[j][2]  = W1[2 * 64 + j];
        sPack[j][3]  = W1[3 * 64 + j];
        sPack[j][4]  = W1[4 * 64 + j];
        sPack[j][5]  = W1[5 * 64 + j];
        sPack[j][6]  = b1[j];
        sPack[j][7]  = 0.f;
        sPack[j][8]  = W2[j * 3 + 0];
        sPack[j][9]  = W2[j * 3 + 1];
        sPack[j][10] = W2[j * 3 + 2];
        sPack[j][11] = 0.f;
    }
    if (tid < 3) sb2[tid] = b2[tid];
    __syncthreads();

    const int wave = tid >> 6;
    const int lane = tid & 63;
    const int ray  = (blockIdx.x << 2) + wave;

    // ---- per-ray data (uniform across wave: broadcast loads) ----
    const float nx = nrm[ray * 3 + 0], ny = nrm[ray * 3 + 1], nz = nrm[ray * 3 + 2];
    const float vx = vd[ray * 3 + 0],  vy = vd[ray * 3 + 1],  vz = vd[ray * 3 + 2];
    const float kd0 = Kd[ray * 3 + 0], kd1 = Kd[ray * 3 + 1], kd2 = Kd[ray * 3 + 2];
    const float ks0 = Ks[ray * 3 + 0], ks1 = Ks[ray * 3 + 1], ks2 = Ks[ray * 3 + 2];
    const float rg  = rough[ray];
    const float spx = sp[ray * 3 + 0], spy = sp[ray * 3 + 1], spz = sp[ray * 3 + 2];

    // ---- frame ----
    const float sgn = (nz >= 0.f) ? 1.f : -1.f;
    const float a   = -1.f / (sgn + nz);
    const float bb  = nx * ny * a;
    const float cx0 = 1.f + sgn * nx * nx * a, cx1 = sgn * bb,          cx2 = -sgn * nx;
    const float cy0 = bb,                      cy1 = sgn + ny * ny * a, cy2 = -ny;
    // cz = (nx,ny,nz)

    // ---- wi ----
    float wi0 = cx0 * vx + cx1 * vy + cx2 * vz;
    float wi1 = cy0 * vx + cy1 * vy + cy2 * vz;
    float wi2 = nx * vx + ny * vy + nz * vz;
    const bool wimask = (wi2 >= 1e-5f);
    wi2 = fmaxf(wi2, 1e-5f);
    {
        const float l2  = wi0 * wi0 + wi1 * wi1 + wi2 * wi2;
        const float inv = rsqrtf(fmaxf(l2, 1e-12f));
        wi0 *= inv; wi1 *= inv; wi2 *= inv;
    }

    const float alpha  = fmaxf(rg * rg, 1e-4f);
    const float alpha2 = alpha * alpha;
    const float dmean  = (kd0 + kd1 + kd2) * (1.f / 3.f);
    const float smean  = (ks0 + ks1 + ks2) * (1.f / 3.f);
    const float pS     = fmaxf(smean / (dmean + smean + 1e-6f), 0.f);

    // ---- per-sample (this lane) ----
    const long  sbase = ((long)ray * SPP_ + lane) * 3;
    const float s0 = smp[sbase + 0];
    const float u1 = smp[sbase + 1];
    const float u2 = smp[sbase + 2];

    const bool  sample_diffuse = (s0 >= pS);
    const float r   = sqrtf(u1);
    const float phi = 2.f * PI_F * u2;
    float sphi, cphi;
    __sincosf(phi, &sphi, &cphi);

    const float ld0 = r * cphi, ld1 = r * sphi;
    const float ld2 = sqrtf(fmaxf(1.f - u1, 0.f));

    float c2 = (1.f - u1) / (1.f + (alpha2 - 1.f) * u1);
    c2 = fminf(fmaxf(c2, 0.f), 1.f);
    const float ct = sqrtf(c2), st = sqrtf(1.f - c2);
    const float h0 = st * cphi, h1 = st * sphi, h2 = ct;

    const float dwh  = wi0 * h0 + wi1 * h1 + wi2 * h2;
    const float lsp0 = 2.f * dwh * h0 - wi0;
    const float lsp1 = 2.f * dwh * h1 - wi1;
    const float lsp2 = 2.f * dwh * h2 - wi2;

    const float wo0 = sample_diffuse ? ld0 : lsp0;
    const float wo1 = sample_diffuse ? ld1 : lsp1;
    const float wo2 = sample_diffuse ? ld2 : lsp2;

    const float pdf_diff = fmaxf(wo2, 0.f) * (1.f / PI_F);

    float hm0 = wi0 + wo0, hm1 = wi1 + wo1, hm2 = wi2 + wo2;
    {
        const float l2  = hm0 * hm0 + hm1 * hm1 + hm2 * hm2;
        const float inv = rsqrtf(fmaxf(l2, 1e-12f));
        hm0 *= inv; hm1 *= inv; hm2 *= inv;
    }
    const float hz = hm2;
    const float dd = hz * hz * (alpha2 - 1.f) + 1.f;
    const float D  = alpha2 / (PI_F * dd * dd);

    const float woh      = wo0 * hm0 + wo1 * hm1 + wo2 * hm2;
    const float pdf_spec = D * fmaxf(hz, 0.f) / (4.f * fmaxf(woh, 1e-6f));
    float pdfs = pS * pdf_spec + (1.f - pS) * pdf_diff;
    pdfs = fmaxf(pdfs, 1e-5f);

    const bool  womask = (wo2 > 0.f);
    const float wiz = fmaxf(wi2, 1e-6f);
    const float woz = fmaxf(wo2, 1e-6f);
    const float G1i = 2.f * wiz / (wiz + sqrtf(alpha2 + (1.f - alpha2) * wiz * wiz));
    const float G1o = 2.f * woz / (woz + sqrtf(alpha2 + (1.f - alpha2) * woz * woz));
    const float G   = G1i * G1o;

    float wih = wi0 * hm0 + wi1 * hm1 + wi2 * hm2;
    wih = fminf(fmaxf(wih, 0.f), 1.f);
    const float t1m = 1.f - wih;
    const float t2s = t1m * t1m;
    const float f5  = t2s * t2s * t1m;
    const float fr0 = ks0 + (1.f - ks0) * f5;
    const float fr1 = ks1 + (1.f - ks1) * f5;
    const float fr2 = ks2 + (1.f - ks2) * f5;

    float ss = D * G / (4.f * wiz * woz);
    if (!womask) ss = 0.f;

    // ---- world direction + MLP feature ----
    const float dx = wo0 * cx0 + wo1 * cy0 + wo2 * nx;
    const float dy = wo0 * cx1 + wo1 * cy1 + wo2 * ny;
    const float dz = wo0 * cx2 + wo1 * cy2 + wo2 * nz;

    const float f0 = spx + 0.01f * dx;
    const float f1 = spy + 0.01f * dy;
    const float f2 = spz + 0.01f * dz;
    const float f3 = dx, f4 = dy, f5f = dz;

    // ---- fused 6->64->3 MLP (unroll 2: small code footprint, enough ILP) ----
    float r0 = sb2[0], r1 = sb2[1], r2 = sb2[2];
    #pragma unroll 2
    for (int j = 0; j < 64; ++j) {
        const float4 p0 = *(const float4*)&sPack[j][0];
        const float4 p1 = *(const float4*)&sPack[j][4];
        const float4 p2 = *(const float4*)&sPack[j][8];
        float h = p1.z;                    // b1[j]
        h = fmaf(f0,  p0.x, h);
        h = fmaf(f1,  p0.y, h);
        h = fmaf(f2,  p0.z, h);
        h = fmaf(f3,  p0.w, h);
        h = fmaf(f4,  p1.x, h);
        h = fmaf(f5f, p1.y, h);
        h = fmaxf(h, 0.f);
        r0 = fmaf(h, p2.x, r0);
        r1 = fmaf(h, p2.y, r1);
        r2 = fmaf(h, p2.z, r2);
    }
    r0 = softplus_f(r0);
    r1 = softplus_f(r1);
    r2 = softplus_f(r2);

    // ---- per-sample contributions ----
    const float ndl = fmaxf(wo2, 0.f);
    const float wgt = ndl / pdfs;

    float ad0 = wgt * r0, ad1 = wgt * r1, ad2 = wgt * r2;
    const float sw = ss * wgt;
    float as0 = sw * fr0 * r0, as1 = sw * fr1 * r1, as2 = sw * fr2 * r2;

    // ---- wave reduction (mean over SPP=64) ----
    #pragma unroll
    for (int off = 32; off > 0; off >>= 1) {
        ad0 += __shfl_down(ad0, off);
        ad1 += __shfl_down(ad1, off);
        ad2 += __shfl_down(ad2, off);
        as0 += __shfl_down(as0, off);
        as1 += __shfl_down(as1, off);
        as2 += __shfl_down(as2, off);
    }

    if (lane == 0) {
        const float cdi = 1.f / (PI_F * (float)SPP_);
        out[ray * 3 + 0] = kd0 * cdi * ad0;
        out[ray * 3 + 1] = kd1 * cdi * ad1;
        out[ray * 3 + 2] = kd2 * cdi * ad2;
        const float csi = 1.f / (float)SPP_;
        out[BN_ * 3 + ray * 3 + 0] = as0 * csi;
        out[BN_ * 3 + ray * 3 + 1] = as1 * csi;
        out[BN_ * 3 + ray * 3 + 2] = as2 * csi;
        out[BN_ * 6 + ray] = wimask ? 1.f : 0.f;
    }
}

extern "C" void kernel_launch(void* const* d_in, const int* in_sizes, int n_in,
                              void* d_out, int out_size, void* d_ws, size_t ws_size,
                              hipStream_t stream) {
    const float* sp    = (const float*)d_in[0];
    const float* vd    = (const float*)d_in[1];
    const float* Kd    = (const float*)d_in[2];
    const float* Ks    = (const float*)d_in[3];
    const float* nrm   = (const float*)d_in[4];
    const float* rough = (const float*)d_in[5];
    const float* smp   = (const float*)d_in[6];
    const float* W1    = (const float*)d_in[7];
    const float* b1    = (const float*)d_in[8];
    const float* W2    = (const float*)d_in[9];
    const float* b2    = (const float*)d_in[10];
    float* out = (float*)d_out;

    dim3 grid(BN_ / 4);
    dim3 block(256);
    render_kernel<<<grid, block, 0, stream>>>(sp, vd, Kd, Ks, nrm, rough, smp,
                                              W1, b1, W2, b2, out);
}

// Round 39
// 75.589 us; speedup vs baseline: 1.2366x; 1.2366x over previous
//
#include <hip/hip_runtime.h>
#include <math.h>

#define BN_ 32768
#define SPP_ 64
#define HID_ 64

__device__ __forceinline__ float softplus_f(float x) {
    return fmaxf(x, 0.f) + log1pf(__expf(-fabsf(x)));
}

struct RayState {
    float f0, f1, f2, f3, f4, f5;   // MLP features
    float kd0, kd1, kd2;
    float wgt, sw;                  // ndl/pdfs, spec_scalar*wgt
    float fr0, fr1, fr2;
    float wim;
};

__device__ __forceinline__ RayState shade_ray(
    const float* __restrict__ sp, const float* __restrict__ vd,
    const float* __restrict__ Kd, const float* __restrict__ Ks,
    const float* __restrict__ nrm, const float* __restrict__ rough,
    const float* __restrict__ smp, int ray, int lane)
{
    const float PI_F = 3.14159265358979323846f;
    RayState S;

    const float nx = nrm[ray * 3 + 0], ny = nrm[ray * 3 + 1], nz = nrm[ray * 3 + 2];
    const float vx = vd[ray * 3 + 0],  vy = vd[ray * 3 + 1],  vz = vd[ray * 3 + 2];
    S.kd0 = Kd[ray * 3 + 0]; S.kd1 = Kd[ray * 3 + 1]; S.kd2 = Kd[ray * 3 + 2];
    const float ks0 = Ks[ray * 3 + 0], ks1 = Ks[ray * 3 + 1], ks2 = Ks[ray * 3 + 2];
    const float rg  = rough[ray];
    const float spx = sp[ray * 3 + 0], spy = sp[ray * 3 + 1], spz = sp[ray * 3 + 2];

    const float sgn = (nz >= 0.f) ? 1.f : -1.f;
    const float a   = -1.f / (sgn + nz);
    const float bb  = nx * ny * a;
    const float cx0 = 1.f + sgn * nx * nx * a, cx1 = sgn * bb,          cx2 = -sgn * nx;
    const float cy0 = bb,                      cy1 = sgn + ny * ny * a, cy2 = -ny;

    float wi0 = cx0 * vx + cx1 * vy + cx2 * vz;
    float wi1 = cy0 * vx + cy1 * vy + cy2 * vz;
    float wi2 = nx * vx + ny * vy + nz * vz;
    S.wim = (wi2 >= 1e-5f) ? 1.f : 0.f;
    wi2 = fmaxf(wi2, 1e-5f);
    {
        const float l2  = wi0 * wi0 + wi1 * wi1 + wi2 * wi2;
        const float inv = rsqrtf(fmaxf(l2, 1e-12f));
        wi0 *= inv; wi1 *= inv; wi2 *= inv;
    }

    const float alpha  = fmaxf(rg * rg, 1e-4f);
    const float alpha2 = alpha * alpha;
    const float dmean  = (S.kd0 + S.kd1 + S.kd2) * (1.f / 3.f);
    const float smean  = (ks0 + ks1 + ks2) * (1.f / 3.f);
    const float pS     = fmaxf(smean / (dmean + smean + 1e-6f), 0.f);

    const long  sbase = ((long)ray * SPP_ + lane) * 3;
    const float s0 = smp[sbase + 0];
    const float u1 = smp[sbase + 1];
    const float u2 = smp[sbase + 2];

    const bool  sample_diffuse = (s0 >= pS);
    const float r   = sqrtf(u1);
    const float phi = 2.f * PI_F * u2;
    float sphi, cphi;
    __sincosf(phi, &sphi, &cphi);

    const float ld0 = r * cphi, ld1 = r * sphi;
    const float ld2 = sqrtf(fmaxf(1.f - u1, 0.f));

    float c2 = (1.f - u1) / (1.f + (alpha2 - 1.f) * u1);
    c2 = fminf(fmaxf(c2, 0.f), 1.f);
    const float ct = sqrtf(c2), st = sqrtf(1.f - c2);
    const float h0 = st * cphi, h1 = st * sphi, h2 = ct;

    const float dwh  = wi0 * h0 + wi1 * h1 + wi2 * h2;
    const float lsp0 = 2.f * dwh * h0 - wi0;
    const float lsp1 = 2.f * dwh * h1 - wi1;
    const float lsp2 = 2.f * dwh * h2 - wi2;

    const float wo0 = sample_diffuse ? ld0 : lsp0;
    const float wo1 = sample_diffuse ? ld1 : lsp1;
    const float wo2 = sample_diffuse ? ld2 : lsp2;

    const float pdf_diff = fmaxf(wo2, 0.f) * (1.f / PI_F);

    float hm0 = wi0 + wo0, hm1 = wi1 + wo1, hm2 = wi2 + wo2;
    {
        const float l2  = hm0 * hm0 + hm1 * hm1 + hm2 * hm2;
        const float inv = rsqrtf(fmaxf(l2, 1e-12f));
        hm0 *= inv; hm1 *= inv; hm2 *= inv;
    }
    const float hz = hm2;
    const float dd = hz * hz * (alpha2 - 1.f) + 1.f;
    const float D  = alpha2 / (PI_F * dd * dd);

    const float woh      = wo0 * hm0 + wo1 * hm1 + wo2 * hm2;
    const float pdf_spec = D * fmaxf(hz, 0.f) / (4.f * fmaxf(woh, 1e-6f));
    float pdfs = pS * pdf_spec + (1.f - pS) * pdf_diff;
    pdfs = fmaxf(pdfs, 1e-5f);

    const bool  womask = (wo2 > 0.f);
    const float wiz = fmaxf(wi2, 1e-6f);
    const float woz = fmaxf(wo2, 1e-6f);
    const float G1i = 2.f * wiz / (wiz + sqrtf(alpha2 + (1.f - alpha2) * wiz * wiz));
    const float G1o = 2.f * woz / (woz + sqrtf(alpha2 + (1.f - alpha2) * woz * woz));
    const float G   = G1i * G1o;

    float wih = wi0 * hm0 + wi1 * hm1 + wi2 * hm2;
    wih = fminf(fmaxf(wih, 0.f), 1.f);
    const float t1m = 1.f - wih;
    const float t2s = t1m * t1m;
    const float f5  = t2s * t2s * t1m;
    S.fr0 = ks0 + (1.f - ks0) * f5;
    S.fr1 = ks1 + (1.f - ks1) * f5;
    S.fr2 = ks2 + (1.f - ks2) * f5;

    float ss = D * G / (4.f * wiz * woz);
    if (!womask) ss = 0.f;

    const float dx = wo0 * cx0 + wo1 * cy0 + wo2 * nx;
    const float dy = wo0 * cx1 + wo1 * cy1 + wo2 * ny;
    const float dz = wo0 * cx2 + wo1 * cy2 + wo2 * nz;

    S.f0 = spx + 0.01f * dx;
    S.f1 = spy + 0.01f * dy;
    S.f2 = spz + 0.01f * dz;
    S.f3 = dx; S.f4 = dy; S.f5 = dz;

    const float ndl = fmaxf(wo2, 0.f);
    S.wgt = ndl / pdfs;
    S.sw  = ss * S.wgt;
    return S;
}

__global__ __launch_bounds__(256) void render_kernel(
    const float* __restrict__ sp, const float* __restrict__ vd,
    const float* __restrict__ Kd, const float* __restrict__ Ks,
    const float* __restrict__ nrm, const float* __restrict__ rough,
    const float* __restrict__ smp,
    const float* __restrict__ W1, const float* __restrict__ b1,
    const float* __restrict__ W2, const float* __restrict__ b2,
    float* __restrict__ out)
{
    const float PI_F = 3.14159265358979323846f;

    __shared__ __align__(16) float sPack[64][12];
    __shared__ float sb2[4];

    const int tid = threadIdx.x;
    if (tid < 64) {
        const int j = tid;
        sPack[j][0]  = W1[0 * 64 + j];
        sPack[j][1]  = W1[1 * 64 + j];
        sPack[j][2]  = W1[2 * 64 + j];
        sPack[j][3]  = W1[3 * 64 + j];
        sPack[j][4]  = W1[4 * 64 + j];
        sPack[j][5]  = W1[5 * 64 + j];
        sPack[j][6]  = b1[j];
        sPack[j][7]  = 0.f;
        sPack[j][8]  = W2[j * 3 + 0];
        sPack[j][9]  = W2[j * 3 + 1];
        sPack[j][10] = W2[j * 3 + 2];
        sPack[j][11] = 0.f;
    }
    if (tid < 3) sb2[tid] = b2[tid];
    __syncthreads();

    const int wave = tid >> 6;
    const int lane = tid & 63;
    // Each wave handles TWO rays: one weight fetch feeds two MLP evals.
    const int rayA = (blockIdx.x << 3) + (wave << 1);
    const int rayB = rayA + 1;

    RayState A = shade_ray(sp, vd, Kd, Ks, nrm, rough, smp, rayA, lane);
    RayState B = shade_ray(sp, vd, Kd, Ks, nrm, rough, smp, rayB, lane);

    // ---- fused dual 6->64->3 MLP (weights read once per j) ----
    float a0 = sb2[0], a1 = sb2[1], a2 = sb2[2];
    float b0 = a0, b1v = a1, b2v = a2;
    #pragma unroll 2
    for (int j = 0; j < 64; ++j) {
        const float4 p0 = *(const float4*)&sPack[j][0];
        const float4 p1 = *(const float4*)&sPack[j][4];
        const float4 p2 = *(const float4*)&sPack[j][8];
        float hA = p1.z;
        hA = fmaf(A.f0, p0.x, hA);
        hA = fmaf(A.f1, p0.y, hA);
        hA = fmaf(A.f2, p0.z, hA);
        hA = fmaf(A.f3, p0.w, hA);
        hA = fmaf(A.f4, p1.x, hA);
        hA = fmaf(A.f5, p1.y, hA);
        hA = fmaxf(hA, 0.f);
        float hB = p1.z;
        hB = fmaf(B.f0, p0.x, hB);
        hB = fmaf(B.f1, p0.y, hB);
        hB = fmaf(B.f2, p0.z, hB);
        hB = fmaf(B.f3, p0.w, hB);
        hB = fmaf(B.f4, p1.x, hB);
        hB = fmaf(B.f5, p1.y, hB);
        hB = fmaxf(hB, 0.f);
        a0  = fmaf(hA, p2.x, a0);
        a1  = fmaf(hA, p2.y, a1);
        a2  = fmaf(hA, p2.z, a2);
        b0  = fmaf(hB, p2.x, b0);
        b1v = fmaf(hB, p2.y, b1v);
        b2v = fmaf(hB, p2.z, b2v);
    }
    a0 = softplus_f(a0); a1 = softplus_f(a1); a2 = softplus_f(a2);
    b0 = softplus_f(b0); b1v = softplus_f(b1v); b2v = softplus_f(b2v);

    // ---- per-sample contributions + wave reductions ----
    float adA0 = A.wgt * a0, adA1 = A.wgt * a1, adA2 = A.wgt * a2;
    float asA0 = A.sw * A.fr0 * a0, asA1 = A.sw * A.fr1 * a1, asA2 = A.sw * A.fr2 * a2;
    float adB0 = B.wgt * b0, adB1 = B.wgt * b1v, adB2 = B.wgt * b2v;
    float asB0 = B.sw * B.fr0 * b0, asB1 = B.sw * B.fr1 * b1v, asB2 = B.sw * B.fr2 * b2v;

    #pragma unroll
    for (int off = 32; off > 0; off >>= 1) {
        adA0 += __shfl_down(adA0, off);
        adA1 += __shfl_down(adA1, off);
        adA2 += __shfl_down(adA2, off);
        asA0 += __shfl_down(asA0, off);
        asA1 += __shfl_down(asA1, off);
        asA2 += __shfl_down(asA2, off);
        adB0 += __shfl_down(adB0, off);
        adB1 += __shfl_down(adB1, off);
        adB2 += __shfl_down(adB2, off);
        asB0 += __shfl_down(asB0, off);
        asB1 += __shfl_down(asB1, off);
        asB2 += __shfl_down(asB2, off);
    }

    if (lane == 0) {
        const float cdi = 1.f / (PI_F * (float)SPP_);
        const float csi = 1.f / (float)SPP_;
        out[rayA * 3 + 0] = A.kd0 * cdi * adA0;
        out[rayA * 3 + 1] = A.kd1 * cdi * adA1;
        out[rayA * 3 + 2] = A.kd2 * cdi * adA2;
        out[BN_ * 3 + rayA * 3 + 0] = asA0 * csi;
        out[BN_ * 3 + rayA * 3 + 1] = asA1 * csi;
        out[BN_ * 3 + rayA * 3 + 2] = asA2 * csi;
        out[BN_ * 6 + rayA] = A.wim;

        out[rayB * 3 + 0] = B.kd0 * cdi * adB0;
        out[rayB * 3 + 1] = B.kd1 * cdi * adB1;
        out[rayB * 3 + 2] = B.kd2 * cdi * adB2;
        out[BN_ * 3 + rayB * 3 + 0] = asB0 * csi;
        out[BN_ * 3 + rayB * 3 + 1] = asB1 * csi;
        out[BN_ * 3 + rayB * 3 + 2] = asB2 * csi;
        out[BN_ * 6 + rayB] = B.wim;
    }
}

extern "C" void kernel_launch(void* const* d_in, const int* in_sizes, int n_in,
                              void* d_out, int out_size, void* d_ws, size_t ws_size,
                              hipStream_t stream) {
    const float* sp    = (const float*)d_in[0];
    const float* vd    = (const float*)d_in[1];
    const float* Kd    = (const float*)d_in[2];
    const float* Ks    = (const float*)d_in[3];
    const float* nrm   = (const float*)d_in[4];
    const float* rough = (const float*)d_in[5];
    const float* smp   = (const float*)d_in[6];
    const float* W1    = (const float*)d_in[7];
    const float* b1    = (const float*)d_in[8];
    const float* W2    = (const float*)d_in[9];
    const float* b2    = (const float*)d_in[10];
    float* out = (float*)d_out;

    dim3 grid(BN_ / 8);
    dim3 block(256);
    render_kernel<<<grid, block, 0, stream>>>(sp, vd, Kd, Ks, nrm, rough, smp,
                                              W1, b1, W2, b2, out);
}

// Round 40
// 71.701 us; speedup vs baseline: 1.3036x; 1.0542x over previous
//
#include <hip/hip_runtime.h>
#include <math.h>

#define BN_ 32768
#define SPP_ 64
#define HID_ 64

typedef float v2f __attribute__((ext_vector_type(2)));

__device__ __forceinline__ v2f pk_fma(v2f a, v2f b, v2f c) {
    v2f d;
    asm("v_pk_fma_f32 %0, %1, %2, %3" : "=v"(d) : "v"(a), "v"(b), "v"(c));
    return d;
}

__device__ __forceinline__ float softplus_f(float x) {
    return fmaxf(x, 0.f) + log1pf(__expf(-fabsf(x)));
}

struct RayState {
    float f0, f1, f2, f3, f4, f5;   // MLP features
    float kd0, kd1, kd2;
    float wgt, sw;                  // ndl/pdfs, spec_scalar*wgt
    float fr0, fr1, fr2;
    float wim;
};

__device__ __forceinline__ RayState shade_ray(
    const float* __restrict__ sp, const float* __restrict__ vd,
    const float* __restrict__ Kd, const float* __restrict__ Ks,
    const float* __restrict__ nrm, const float* __restrict__ rough,
    const float* __restrict__ smp, int ray, int lane)
{
    const float PI_F = 3.14159265358979323846f;
    RayState S;

    const float nx = nrm[ray * 3 + 0], ny = nrm[ray * 3 + 1], nz = nrm[ray * 3 + 2];
    const float vx = vd[ray * 3 + 0],  vy = vd[ray * 3 + 1],  vz = vd[ray * 3 + 2];
    S.kd0 = Kd[ray * 3 + 0]; S.kd1 = Kd[ray * 3 + 1]; S.kd2 = Kd[ray * 3 + 2];
    const float ks0 = Ks[ray * 3 + 0], ks1 = Ks[ray * 3 + 1], ks2 = Ks[ray * 3 + 2];
    const float rg  = rough[ray];
    const float spx = sp[ray * 3 + 0], spy = sp[ray * 3 + 1], spz = sp[ray * 3 + 2];

    const float sgn = (nz >= 0.f) ? 1.f : -1.f;
    const float a   = -1.f / (sgn + nz);
    const float bb  = nx * ny * a;
    const float cx0 = 1.f + sgn * nx * nx * a, cx1 = sgn * bb,          cx2 = -sgn * nx;
    const float cy0 = bb,                      cy1 = sgn + ny * ny * a, cy2 = -ny;

    float wi0 = cx0 * vx + cx1 * vy + cx2 * vz;
    float wi1 = cy0 * vx + cy1 * vy + cy2 * vz;
    float wi2 = nx * vx + ny * vy + nz * vz;
    S.wim = (wi2 >= 1e-5f) ? 1.f : 0.f;
    wi2 = fmaxf(wi2, 1e-5f);
    {
        const float l2  = wi0 * wi0 + wi1 * wi1 + wi2 * wi2;
        const float inv = rsqrtf(fmaxf(l2, 1e-12f));
        wi0 *= inv; wi1 *= inv; wi2 *= inv;
    }

    const float alpha  = fmaxf(rg * rg, 1e-4f);
    const float alpha2 = alpha * alpha;
    const float dmean  = (S.kd0 + S.kd1 + S.kd2) * (1.f / 3.f);
    const float smean  = (ks0 + ks1 + ks2) * (1.f / 3.f);
    const float pS     = fmaxf(smean / (dmean + smean + 1e-6f), 0.f);

    const long  sbase = ((long)ray * SPP_ + lane) * 3;
    const float s0 = smp[sbase + 0];
    const float u1 = smp[sbase + 1];
    const float u2 = smp[sbase + 2];

    const bool  sample_diffuse = (s0 >= pS);
    const float r   = sqrtf(u1);
    const float phi = 2.f * PI_F * u2;
    float sphi, cphi;
    __sincosf(phi, &sphi, &cphi);

    const float ld0 = r * cphi, ld1 = r * sphi;
    const float ld2 = sqrtf(fmaxf(1.f - u1, 0.f));

    float c2 = (1.f - u1) / (1.f + (alpha2 - 1.f) * u1);
    c2 = fminf(fmaxf(c2, 0.f), 1.f);
    const float ct = sqrtf(c2), st = sqrtf(1.f - c2);
    const float h0 = st * cphi, h1 = st * sphi, h2 = ct;

    const float dwh  = wi0 * h0 + wi1 * h1 + wi2 * h2;
    const float lsp0 = 2.f * dwh * h0 - wi0;
    const float lsp1 = 2.f * dwh * h1 - wi1;
    const float lsp2 = 2.f * dwh * h2 - wi2;

    const float wo0 = sample_diffuse ? ld0 : lsp0;
    const float wo1 = sample_diffuse ? ld1 : lsp1;
    const float wo2 = sample_diffuse ? ld2 : lsp2;

    const float pdf_diff = fmaxf(wo2, 0.f) * (1.f / PI_F);

    float hm0 = wi0 + wo0, hm1 = wi1 + wo1, hm2 = wi2 + wo2;
    {
        const float l2  = hm0 * hm0 + hm1 * hm1 + hm2 * hm2;
        const float inv = rsqrtf(fmaxf(l2, 1e-12f));
        hm0 *= inv; hm1 *= inv; hm2 *= inv;
    }
    const float hz = hm2;
    const float dd = hz * hz * (alpha2 - 1.f) + 1.f;
    const float D  = alpha2 / (PI_F * dd * dd);

    const float woh      = wo0 * hm0 + wo1 * hm1 + wo2 * hm2;
    const float pdf_spec = D * fmaxf(hz, 0.f) / (4.f * fmaxf(woh, 1e-6f));
    float pdfs = pS * pdf_spec + (1.f - pS) * pdf_diff;
    pdfs = fmaxf(pdfs, 1e-5f);

    const bool  womask = (wo2 > 0.f);
    const float wiz = fmaxf(wi2, 1e-6f);
    const float woz = fmaxf(wo2, 1e-6f);
    const float G1i = 2.f * wiz / (wiz + sqrtf(alpha2 + (1.f - alpha2) * wiz * wiz));
    const float G1o = 2.f * woz / (woz + sqrtf(alpha2 + (1.f - alpha2) * woz * woz));
    const float G   = G1i * G1o;

    float wih = wi0 * hm0 + wi1 * hm1 + wi2 * hm2;
    wih = fminf(fmaxf(wih, 0.f), 1.f);
    const float t1m = 1.f - wih;
    const float t2s = t1m * t1m;
    const float f5  = t2s * t2s * t1m;
    S.fr0 = ks0 + (1.f - ks0) * f5;
    S.fr1 = ks1 + (1.f - ks1) * f5;
    S.fr2 = ks2 + (1.f - ks2) * f5;

    float ss = D * G / (4.f * wiz * woz);
    if (!womask) ss = 0.f;

    const float dx = wo0 * cx0 + wo1 * cy0 + wo2 * nx;
    const float dy = wo0 * cx1 + wo1 * cy1 + wo2 * ny;
    const float dz = wo0 * cx2 + wo1 * cy2 + wo2 * nz;

    S.f0 = spx + 0.01f * dx;
    S.f1 = spy + 0.01f * dy;
    S.f2 = spz + 0.01f * dz;
    S.f3 = dx; S.f4 = dy; S.f5 = dz;

    const float ndl = fmaxf(wo2, 0.f);
    S.wgt = ndl / pdfs;
    S.sw  = ss * S.wgt;
    return S;
}

__global__ __launch_bounds__(256) void render_kernel(
    const float* __restrict__ sp, const float* __restrict__ vd,
    const float* __restrict__ Kd, const float* __restrict__ Ks,
    const float* __restrict__ nrm, const float* __restrict__ rough,
    const float* __restrict__ smp,
    const float* __restrict__ W1, const float* __restrict__ b1,
    const float* __restrict__ W2, const float* __restrict__ b2,
    float* __restrict__ out)
{
    const float PI_F = 3.14159265358979323846f;

    // Pair-packed weights: row p (p=0..31) covers hidden units 2p, 2p+1.
    // [0..11]: {W1[k][2p],W1[k][2p+1]} k=0..5 | [12..13]: b1 pair |
    // [14..19]: {W2[2p][c],W2[2p+1][c]} c=0..2.  Row = 80B (16B-aligned).
    __shared__ __align__(16) float sPk[32][20];
    __shared__ float sb2[4];

    const int tid = threadIdx.x;
    if (tid < 32) {
        const int p = tid, j0 = 2 * tid, j1 = 2 * tid + 1;
        #pragma unroll
        for (int k = 0; k < 6; ++k) {
            sPk[p][2 * k + 0] = W1[k * 64 + j0];
            sPk[p][2 * k + 1] = W1[k * 64 + j1];
        }
        sPk[p][12] = b1[j0];
        sPk[p][13] = b1[j1];
        #pragma unroll
        for (int c = 0; c < 3; ++c) {
            sPk[p][14 + 2 * c] = W2[j0 * 3 + c];
            sPk[p][15 + 2 * c] = W2[j1 * 3 + c];
        }
    }
    if (tid < 3) sb2[tid] = b2[tid];
    __syncthreads();

    const int wave = tid >> 6;
    const int lane = tid & 63;
    const int rayA = (blockIdx.x << 3) + (wave << 1);
    const int rayB = rayA + 1;

    RayState A = shade_ray(sp, vd, Kd, Ks, nrm, rough, smp, rayA, lane);
    RayState B = shade_ray(sp, vd, Kd, Ks, nrm, rough, smp, rayB, lane);

    // Loop-invariant duplicated features.
    const v2f fA0 = {A.f0, A.f0}, fA1 = {A.f1, A.f1}, fA2 = {A.f2, A.f2};
    const v2f fA3 = {A.f3, A.f3}, fA4 = {A.f4, A.f4}, fA5 = {A.f5, A.f5};
    const v2f fB0 = {B.f0, B.f0}, fB1 = {B.f1, B.f1}, fB2 = {B.f2, B.f2};
    const v2f fB3 = {B.f3, B.f3}, fB4 = {B.f4, B.f4}, fB5 = {B.f5, B.f5};

    v2f accA0 = {0.f, 0.f}, accA1 = {0.f, 0.f}, accA2 = {0.f, 0.f};
    v2f accB0 = {0.f, 0.f}, accB1 = {0.f, 0.f}, accB2 = {0.f, 0.f};

    #pragma unroll 2
    for (int p = 0; p < 32; ++p) {
        const float4 q0 = *(const float4*)&sPk[p][0];
        const float4 q1 = *(const float4*)&sPk[p][4];
        const float4 q2 = *(const float4*)&sPk[p][8];
        const float4 q3 = *(const float4*)&sPk[p][12];
        const float4 q4 = *(const float4*)&sPk[p][16];
        const v2f w0 = {q0.x, q0.y}, w1 = {q0.z, q0.w};
        const v2f w2 = {q1.x, q1.y}, w3 = {q1.z, q1.w};
        const v2f w4 = {q2.x, q2.y}, w5 = {q2.z, q2.w};
        const v2f b1p = {q3.x, q3.y};
        const v2f u0 = {q3.z, q3.w}, u1 = {q4.x, q4.y}, u2 = {q4.z, q4.w};

        v2f hA = pk_fma(fA0, w0, b1p);
        hA = pk_fma(fA1, w1, hA);
        hA = pk_fma(fA2, w2, hA);
        hA = pk_fma(fA3, w3, hA);
        hA = pk_fma(fA4, w4, hA);
        hA = pk_fma(fA5, w5, hA);
        hA.x = fmaxf(hA.x, 0.f);
        hA.y = fmaxf(hA.y, 0.f);

        v2f hB = pk_fma(fB0, w0, b1p);
        hB = pk_fma(fB1, w1, hB);
        hB = pk_fma(fB2, w2, hB);
        hB = pk_fma(fB3, w3, hB);
        hB = pk_fma(fB4, w4, hB);
        hB = pk_fma(fB5, w5, hB);
        hB.x = fmaxf(hB.x, 0.f);
        hB.y = fmaxf(hB.y, 0.f);

        accA0 = pk_fma(hA, u0, accA0);
        accA1 = pk_fma(hA, u1, accA1);
        accA2 = pk_fma(hA, u2, accA2);
        accB0 = pk_fma(hB, u0, accB0);
        accB1 = pk_fma(hB, u1, accB1);
        accB2 = pk_fma(hB, u2, accB2);
    }

    float a0 = softplus_f(accA0.x + accA0.y + sb2[0]);
    float a1 = softplus_f(accA1.x + accA1.y + sb2[1]);
    float a2 = softplus_f(accA2.x + accA2.y + sb2[2]);
    float b0 = softplus_f(accB0.x + accB0.y + sb2[0]);
    float b1v = softplus_f(accB1.x + accB1.y + sb2[1]);
    float b2v = softplus_f(accB2.x + accB2.y + sb2[2]);

    float adA0 = A.wgt * a0, adA1 = A.wgt * a1, adA2 = A.wgt * a2;
    float asA0 = A.sw * A.fr0 * a0, asA1 = A.sw * A.fr1 * a1, asA2 = A.sw * A.fr2 * a2;
    float adB0 = B.wgt * b0, adB1 = B.wgt * b1v, adB2 = B.wgt * b2v;
    float asB0 = B.sw * B.fr0 * b0, asB1 = B.sw * B.fr1 * b1v, asB2 = B.sw * B.fr2 * b2v;

    #pragma unroll
    for (int off = 32; off > 0; off >>= 1) {
        adA0 += __shfl_down(adA0, off);
        adA1 += __shfl_down(adA1, off);
        adA2 += __shfl_down(adA2, off);
        asA0 += __shfl_down(asA0, off);
        asA1 += __shfl_down(asA1, off);
        asA2 += __shfl_down(asA2, off);
        adB0 += __shfl_down(adB0, off);
        adB1 += __shfl_down(adB1, off);
        adB2 += __shfl_down(adB2, off);
        asB0 += __shfl_down(asB0, off);
        asB1 += __shfl_down(asB1, off);
        asB2 += __shfl_down(asB2, off);
    }

    if (lane == 0) {
        const float cdi = 1.f / (PI_F * (float)SPP_);
        const float csi = 1.f / (float)SPP_;
        out[rayA * 3 + 0] = A.kd0 * cdi * adA0;
        out[rayA * 3 + 1] = A.kd1 * cdi * adA1;
        out[rayA * 3 + 2] = A.kd2 * cdi * adA2;
        out[BN_ * 3 + rayA * 3 + 0] = asA0 * csi;
        out[BN_ * 3 + rayA * 3 + 1] = asA1 * csi;
        out[BN_ * 3 + rayA * 3 + 2] = asA2 * csi;
        out[BN_ * 6 + rayA] = A.wim;

        out[rayB * 3 + 0] = B.kd0 * cdi * adB0;
        out[rayB * 3 + 1] = B.kd1 * cdi * adB1;
        out[rayB * 3 + 2] = B.kd2 * cdi * adB2;
        out[BN_ * 3 + rayB * 3 + 0] = asB0 * csi;
        out[BN_ * 3 + rayB * 3 + 1] = asB1 * csi;
        out[BN_ * 3 + rayB * 3 + 2] = asB2 * csi;
        out[BN_ * 6 + rayB] = B.wim;
    }
}

extern "C" void kernel_launch(void* const* d_in, const int* in_sizes, int n_in,
                              void* d_out, int out_size, void* d_ws, size_t ws_size,
                              hipStream_t stream) {
    const float* sp    = (const float*)d_in[0];
    const float* vd    = (const float*)d_in[1];
    const float* Kd    = (const float*)d_in[2];
    const float* Ks    = (const float*)d_in[3];
    const float* nrm   = (const float*)d_in[4];
    const float* rough = (const float*)d_in[5];
    const float* smp   = (const float*)d_in[6];
    const float* W1    = (const float*)d_in[7];
    const float* b1    = (const float*)d_in[8];
    const float* W2    = (const float*)d_in[9];
    const float* b2    = (const float*)d_in[10];
    float* out = (float*)d_out;

    dim3 grid(BN_ / 8);
    dim3 block(256);
    render_kernel<<<grid, block, 0, stream>>>(sp, vd, Kd, Ks, nrm, rough, smp,
                                              W1, b1, W2, b2, out);
}

// Round 41
// 56.815 us; speedup vs baseline: 1.6452x; 1.2620x over previous
//
#include <hip/hip_runtime.h>
#include <math.h>

#define BN_ 32768
#define SPP_ 64
#define HID_ 64

typedef float v2f __attribute__((ext_vector_type(2)));

__device__ __forceinline__ v2f pk_fma(v2f a, v2f b, v2f c) {
    v2f d;
    asm("v_pk_fma_f32 %0, %1, %2, %3" : "=v"(d) : "v"(a), "v"(b), "v"(c));
    return d;
}

__device__ __forceinline__ float softplus_f(float x) {
    return fmaxf(x, 0.f) + __logf(1.f + __expf(-fabsf(x)));
}

struct RayState {
    float f0, f1, f2, f3, f4, f5;   // MLP features
    float wgt, sw;                  // ndl/pdfs, spec_scalar*wgt
    float fr0, fr1, fr2;
    float wim;
};

__device__ __forceinline__ RayState shade_ray(
    const float* __restrict__ sp, const float* __restrict__ vd,
    const float* __restrict__ Kd, const float* __restrict__ Ks,
    const float* __restrict__ nrm, const float* __restrict__ rough,
    const float* __restrict__ smp, int ray, int lane)
{
    const float PI_F = 3.14159265358979323846f;
    RayState S;

    const float nx = nrm[ray * 3 + 0], ny = nrm[ray * 3 + 1], nz = nrm[ray * 3 + 2];
    const float vx = vd[ray * 3 + 0],  vy = vd[ray * 3 + 1],  vz = vd[ray * 3 + 2];
    const float kd0 = Kd[ray * 3 + 0], kd1 = Kd[ray * 3 + 1], kd2 = Kd[ray * 3 + 2];
    const float ks0 = Ks[ray * 3 + 0], ks1 = Ks[ray * 3 + 1], ks2 = Ks[ray * 3 + 2];
    const float rg  = rough[ray];
    const float spx = sp[ray * 3 + 0], spy = sp[ray * 3 + 1], spz = sp[ray * 3 + 2];

    const float sgn = (nz >= 0.f) ? 1.f : -1.f;
    const float a   = __fdividef(-1.f, sgn + nz);
    const float bb  = nx * ny * a;
    const float cx0 = 1.f + sgn * nx * nx * a, cx1 = sgn * bb,          cx2 = -sgn * nx;
    const float cy0 = bb,                      cy1 = sgn + ny * ny * a, cy2 = -ny;

    float wi0 = cx0 * vx + cx1 * vy + cx2 * vz;
    float wi1 = cy0 * vx + cy1 * vy + cy2 * vz;
    float wi2 = nx * vx + ny * vy + nz * vz;
    S.wim = (wi2 >= 1e-5f) ? 1.f : 0.f;
    wi2 = fmaxf(wi2, 1e-5f);
    {
        const float l2  = wi0 * wi0 + wi1 * wi1 + wi2 * wi2;
        const float inv = rsqrtf(fmaxf(l2, 1e-12f));
        wi0 *= inv; wi1 *= inv; wi2 *= inv;
    }

    const float alpha  = fmaxf(rg * rg, 1e-4f);
    const float alpha2 = alpha * alpha;
    const float dmean  = (kd0 + kd1 + kd2) * (1.f / 3.f);
    const float smean  = (ks0 + ks1 + ks2) * (1.f / 3.f);
    const float pS     = fmaxf(__fdividef(smean, dmean + smean + 1e-6f), 0.f);

    const long  sbase = ((long)ray * SPP_ + lane) * 3;
    const float s0 = smp[sbase + 0];
    const float u1 = smp[sbase + 1];
    const float u2 = smp[sbase + 2];

    const bool  sample_diffuse = (s0 >= pS);
    const float r   = __builtin_amdgcn_sqrtf(u1);
    // sin(2*pi*u2): v_sin/v_cos take revolutions, u2 in [0,1)
    const float sphi = __builtin_amdgcn_sinf(u2);
    const float cphi = __builtin_amdgcn_cosf(u2);

    const float ld0 = r * cphi, ld1 = r * sphi;
    const float ld2 = __builtin_amdgcn_sqrtf(fmaxf(1.f - u1, 0.f));

    float c2 = __fdividef(1.f - u1, 1.f + (alpha2 - 1.f) * u1);
    c2 = fminf(fmaxf(c2, 0.f), 1.f);
    const float ct = __builtin_amdgcn_sqrtf(c2);
    const float st = __builtin_amdgcn_sqrtf(1.f - c2);
    const float h0 = st * cphi, h1 = st * sphi, h2 = ct;

    const float dwh  = wi0 * h0 + wi1 * h1 + wi2 * h2;
    const float lsp0 = 2.f * dwh * h0 - wi0;
    const float lsp1 = 2.f * dwh * h1 - wi1;
    const float lsp2 = 2.f * dwh * h2 - wi2;

    const float wo0 = sample_diffuse ? ld0 : lsp0;
    const float wo1 = sample_diffuse ? ld1 : lsp1;
    const float wo2 = sample_diffuse ? ld2 : lsp2;

    const float pdf_diff = fmaxf(wo2, 0.f) * (1.f / PI_F);

    float hm0 = wi0 + wo0, hm1 = wi1 + wo1, hm2 = wi2 + wo2;
    {
        const float l2  = hm0 * hm0 + hm1 * hm1 + hm2 * hm2;
        const float inv = rsqrtf(fmaxf(l2, 1e-12f));
        hm0 *= inv; hm1 *= inv; hm2 *= inv;
    }
    const float hz = hm2;
    const float dd = hz * hz * (alpha2 - 1.f) + 1.f;
    const float D  = __fdividef(alpha2, PI_F * dd * dd);

    const float woh      = wo0 * hm0 + wo1 * hm1 + wo2 * hm2;
    const float pdf_spec = __fdividef(D * fmaxf(hz, 0.f), 4.f * fmaxf(woh, 1e-6f));
    float pdfs = pS * pdf_spec + (1.f - pS) * pdf_diff;
    pdfs = fmaxf(pdfs, 1e-5f);

    const bool  womask = (wo2 > 0.f);
    const float wiz = fmaxf(wi2, 1e-6f);
    const float woz = fmaxf(wo2, 1e-6f);
    const float G1i = __fdividef(2.f * wiz,
        wiz + __builtin_amdgcn_sqrtf(alpha2 + (1.f - alpha2) * wiz * wiz));
    const float G1o = __fdividef(2.f * woz,
        woz + __builtin_amdgcn_sqrtf(alpha2 + (1.f - alpha2) * woz * woz));
    const float G   = G1i * G1o;

    float wih = wi0 * hm0 + wi1 * hm1 + wi2 * hm2;
    wih = fminf(fmaxf(wih, 0.f), 1.f);
    const float t1m = 1.f - wih;
    const float t2s = t1m * t1m;
    const float f5  = t2s * t2s * t1m;
    S.fr0 = ks0 + (1.f - ks0) * f5;
    S.fr1 = ks1 + (1.f - ks1) * f5;
    S.fr2 = ks2 + (1.f - ks2) * f5;

    float ss = __fdividef(D * G, 4.f * wiz * woz);
    if (!womask) ss = 0.f;

    const float dx = wo0 * cx0 + wo1 * cy0 + wo2 * nx;
    const float dy = wo0 * cx1 + wo1 * cy1 + wo2 * ny;
    const float dz = wo0 * cx2 + wo1 * cy2 + wo2 * nz;

    S.f0 = spx + 0.01f * dx;
    S.f1 = spy + 0.01f * dy;
    S.f2 = spz + 0.01f * dz;
    S.f3 = dx; S.f4 = dy; S.f5 = dz;

    const float ndl = fmaxf(wo2, 0.f);
    S.wgt = __fdividef(ndl, pdfs);
    S.sw  = ss * S.wgt;
    return S;
}

__global__ __launch_bounds__(256) void render_kernel(
    const float* __restrict__ sp, const float* __restrict__ vd,
    const float* __restrict__ Kd, const float* __restrict__ Ks,
    const float* __restrict__ nrm, const float* __restrict__ rough,
    const float* __restrict__ smp,
    const float* __restrict__ W1, const float* __restrict__ b1,
    const float* __restrict__ W2, const float* __restrict__ b2,
    float* __restrict__ out)
{
    const float PI_F = 3.14159265358979323846f;

    // Pair-packed weights: row p (p=0..31) covers hidden units 2p, 2p+1.
    __shared__ __align__(16) float sPk[32][20];
    __shared__ float sb2[4];

    const int tid = threadIdx.x;
    if (tid < 32) {
        const int p = tid, j0 = 2 * tid, j1 = 2 * tid + 1;
        #pragma unroll
        for (int k = 0; k < 6; ++k) {
            sPk[p][2 * k + 0] = W1[k * 64 + j0];
            sPk[p][2 * k + 1] = W1[k * 64 + j1];
        }
        sPk[p][12] = b1[j0];
        sPk[p][13] = b1[j1];
        #pragma unroll
        for (int c = 0; c < 3; ++c) {
            sPk[p][14 + 2 * c] = W2[j0 * 3 + c];
            sPk[p][15 + 2 * c] = W2[j1 * 3 + c];
        }
    }
    if (tid < 3) sb2[tid] = b2[tid];
    __syncthreads();

    const int wave = tid >> 6;
    const int lane = tid & 63;
    const int rayA = (blockIdx.x << 3) + (wave << 1);
    const int rayB = rayA + 1;

    RayState A = shade_ray(sp, vd, Kd, Ks, nrm, rough, smp, rayA, lane);
    RayState B = shade_ray(sp, vd, Kd, Ks, nrm, rough, smp, rayB, lane);

    const v2f fA0 = {A.f0, A.f0}, fA1 = {A.f1, A.f1}, fA2 = {A.f2, A.f2};
    const v2f fA3 = {A.f3, A.f3}, fA4 = {A.f4, A.f4}, fA5 = {A.f5, A.f5};
    const v2f fB0 = {B.f0, B.f0}, fB1 = {B.f1, B.f1}, fB2 = {B.f2, B.f2};
    const v2f fB3 = {B.f3, B.f3}, fB4 = {B.f4, B.f4}, fB5 = {B.f5, B.f5};

    v2f accA0 = {0.f, 0.f}, accA1 = {0.f, 0.f}, accA2 = {0.f, 0.f};
    v2f accB0 = {0.f, 0.f}, accB1 = {0.f, 0.f}, accB2 = {0.f, 0.f};

    #pragma unroll 2
    for (int p = 0; p < 32; ++p) {
        const float4 q0 = *(const float4*)&sPk[p][0];
        const float4 q1 = *(const float4*)&sPk[p][4];
        const float4 q2 = *(const float4*)&sPk[p][8];
        const float4 q3 = *(const float4*)&sPk[p][12];
        const float4 q4 = *(const float4*)&sPk[p][16];
        const v2f w0 = {q0.x, q0.y}, w1 = {q0.z, q0.w};
        const v2f w2 = {q1.x, q1.y}, w3 = {q1.z, q1.w};
        const v2f w4 = {q2.x, q2.y}, w5 = {q2.z, q2.w};
        const v2f b1p = {q3.x, q3.y};
        const v2f u0 = {q3.z, q3.w}, u1 = {q4.x, q4.y}, u2 = {q4.z, q4.w};

        v2f hA = pk_fma(fA0, w0, b1p);
        hA = pk_fma(fA1, w1, hA);
        hA = pk_fma(fA2, w2, hA);
        hA = pk_fma(fA3, w3, hA);
        hA = pk_fma(fA4, w4, hA);
        hA = pk_fma(fA5, w5, hA);
        hA.x = fmaxf(hA.x, 0.f);
        hA.y = fmaxf(hA.y, 0.f);

        v2f hB = pk_fma(fB0, w0, b1p);
        hB = pk_fma(fB1, w1, hB);
        hB = pk_fma(fB2, w2, hB);
        hB = pk_fma(fB3, w3, hB);
        hB = pk_fma(fB4, w4, hB);
        hB = pk_fma(fB5, w5, hB);
        hB.x = fmaxf(hB.x, 0.f);
        hB.y = fmaxf(hB.y, 0.f);

        accA0 = pk_fma(hA, u0, accA0);
        accA1 = pk_fma(hA, u1, accA1);
        accA2 = pk_fma(hA, u2, accA2);
        accB0 = pk_fma(hB, u0, accB0);
        accB1 = pk_fma(hB, u1, accB1);
        accB2 = pk_fma(hB, u2, accB2);
    }

    float a0 = softplus_f(accA0.x + accA0.y + sb2[0]);
    float a1 = softplus_f(accA1.x + accA1.y + sb2[1]);
    float a2 = softplus_f(accA2.x + accA2.y + sb2[2]);
    float b0 = softplus_f(accB0.x + accB0.y + sb2[0]);
    float b1v = softplus_f(accB1.x + accB1.y + sb2[1]);
    float b2v = softplus_f(accB2.x + accB2.y + sb2[2]);

    float adA0 = A.wgt * a0, adA1 = A.wgt * a1, adA2 = A.wgt * a2;
    float asA0 = A.sw * A.fr0 * a0, asA1 = A.sw * A.fr1 * a1, asA2 = A.sw * A.fr2 * a2;
    float adB0 = B.wgt * b0, adB1 = B.wgt * b1v, adB2 = B.wgt * b2v;
    float asB0 = B.sw * B.fr0 * b0, asB1 = B.sw * B.fr1 * b1v, asB2 = B.sw * B.fr2 * b2v;

    #pragma unroll
    for (int off = 32; off > 0; off >>= 1) {
        adA0 += __shfl_down(adA0, off);
        adA1 += __shfl_down(adA1, off);
        adA2 += __shfl_down(adA2, off);
        asA0 += __shfl_down(asA0, off);
        asA1 += __shfl_down(asA1, off);
        asA2 += __shfl_down(asA2, off);
        adB0 += __shfl_down(adB0, off);
        adB1 += __shfl_down(adB1, off);
        adB2 += __shfl_down(adB2, off);
        asB0 += __shfl_down(asB0, off);
        asB1 += __shfl_down(asB1, off);
        asB2 += __shfl_down(asB2, off);
    }

    if (lane == 0) {
        const float cdi = 1.f / (PI_F * (float)SPP_);
        const float csi = 1.f / (float)SPP_;
        out[rayA * 3 + 0] = Kd[rayA * 3 + 0] * cdi * adA0;
        out[rayA * 3 + 1] = Kd[rayA * 3 + 1] * cdi * adA1;
        out[rayA * 3 + 2] = Kd[rayA * 3 + 2] * cdi * adA2;
        out[BN_ * 3 + rayA * 3 + 0] = asA0 * csi;
        out[BN_ * 3 + rayA * 3 + 1] = asA1 * csi;
        out[BN_ * 3 + rayA * 3 + 2] = asA2 * csi;
        out[BN_ * 6 + rayA] = A.wim;

        out[rayB * 3 + 0] = Kd[rayB * 3 + 0] * cdi * adB0;
        out[rayB * 3 + 1] = Kd[rayB * 3 + 1] * cdi * adB1;
        out[rayB * 3 + 2] = Kd[rayB * 3 + 2] * cdi * adB2;
        out[BN_ * 3 + rayB * 3 + 0] = asB0 * csi;
        out[BN_ * 3 + rayB * 3 + 1] = asB1 * csi;
        out[BN_ * 3 + rayB * 3 + 2] = asB2 * csi;
        out[BN_ * 6 + rayB] = B.wim;
    }
}

extern "C" void kernel_launch(void* const* d_in, const int* in_sizes, int n_in,
                              void* d_out, int out_size, void* d_ws, size_t ws_size,
                              hipStream_t stream) {
    const float* sp    = (const float*)d_in[0];
    const float* vd    = (const float*)d_in[1];
    const float* Kd    = (const float*)d_in[2];
    const float* Ks    = (const float*)d_in[3];
    const float* nrm   = (const float*)d_in[4];
    const float* rough = (const float*)d_in[5];
    const float* smp   = (const float*)d_in[6];
    const float* W1    = (const float*)d_in[7];
    const float* b1    = (const float*)d_in[8];
    const float* W2    = (const float*)d_in[9];
    const float* b2    = (const float*)d_in[10];
    float* out = (float*)d_out;

    dim3 grid(BN_ / 8);
    dim3 block(256);
    render_kernel<<<grid, block, 0, stream>>>(sp, vd, Kd, Ks, nrm, rough, smp,
                                              W1, b1, W2, b2, out);
}